// Round 7
// baseline (37.780 us; speedup 1.0000x reference)
//
#include <hip/hip_runtime.h>

#define HH 160
#define WW 160
#define HW (HH*WW)
#define NB 16
#define NM 64
#define NC 43
#define BLKX 25                  // blocks per image, 1024 px each (256 thr x 4 px)
#define NBLK (NB*BLKX)           // 400 blocks total

constexpr float STRIDE = 4.0f;   // 640 / 160
constexpr float EPSF = 1e-7f;
constexpr float BIGF = 3.4e38f;

// acc layout (f64): q*16 + b, q in {0:hs 1:hc 2:l1 3:mc 4:cs 5:cp}; ticket at +768B

// Shared geometry: must be bit-identical everywhere it is evaluated.
__device__ __forceinline__ void box_geom4(const float4* __restrict__ bb4,
                                          const int* __restrict__ labels, int t,
                                          bool& valid, int& gx, int& gy,
                                          float& cx, float& cy, float& bw, float& bh) {
  float4 v = bb4[t];
  cx = (v.x + v.z) * 0.5f;
  cy = (v.y + v.w) * 0.5f;
  bw = v.z - v.x;
  bh = v.w - v.y;
  int lab = labels[t];
  valid = (lab >= 0) && ((v.x + v.y + v.z + v.w) > 0.0f) && (bw > 0.0f) && (bh > 0.0f);
  int tgx = (int)(cx * 0.25f);            // /4 exact; trunc matches astype(int32)
  int tgy = (int)(cy * 0.25f);
  gx = tgx < 0 ? 0 : (tgx > WW - 1 ? WW - 1 : tgx);
  gy = tgy < 0 ? 0 : (tgy > HH - 1 ? HH - 1 : tgy);
}

// Single kernel: heat focal (all blocks) + winner cells (bx<16) + atomic-coherent
// last-block finalize. NO fences, NO cache-maintenance ops — all cross-block data
// moves through device-scope atomics only.
__global__ __launch_bounds__(256) void k_all(const float* __restrict__ pred_heat,
                                             const float* __restrict__ pred_boxes,
                                             const float* __restrict__ pred_classes,
                                             const float4* __restrict__ bboxes,
                                             const int* __restrict__ labels,
                                             double* __restrict__ acc,
                                             unsigned int* __restrict__ ticket,
                                             float* __restrict__ out) {
  __shared__ float4 sp[NM];                // (z, -2z*gx, -2z*gy, z*(gx^2+gy^2) | NaN)
  __shared__ int islast;
  __shared__ double fin[96];

  int b = blockIdx.y, bx = blockIdx.x;
  int tid = threadIdx.x;
  int wave = tid >> 6, lane = tid & 63;

  if (tid < NM) {
    int t = b * NM + tid;
    bool valid; int gx, gy; float cx, cy, bw, bh;
    box_geom4(bboxes, labels, t, valid, gx, gy, cx, cy, bw, bh);
    float rf = fmaxf(sqrtf(bw * bh) * 0.25f, 2.0f);   // fmax(NaN,2)=2 for junk boxes
    float r = (float)(int)rf;
    float z = 2.0f / (r * r);              // 1/(2*sigma^2); covered iff a <= 8
    float gxf = (float)gx, gyf = (float)gy;
    float4 p;
    p.x = z;
    p.y = -2.0f * z * gxf;
    p.z = -2.0f * z * gyf;
    p.w = valid ? z * fmaf(gxf, gxf, gyf * gyf) : __int_as_float(0x7fc00000);
    sp[tid] = p;                           // NaN K => a=NaN => v_min_f32 skips (IEEE)
  }
  __syncthreads();

  // ---- heat: 4 px/thread (4-aligned chunk never straddles a row; 4|160) ----
  int pixbase = bx * 1024 + tid * 4;       // within image
  int idx = b * HW + pixbase;
  float4 pr4 = *(const float4*)(pred_heat + idx);    // coalesced 16B, issued early
  int row = pixbase / WW;
  float xf0 = (float)(pixbase - row * WW);
  float yf = (float)row;
  float xf1 = xf0 + 1.0f, xf2 = xf0 + 2.0f, xf3 = xf0 + 3.0f;
  float yy = yf * yf;
  float s0 = fmaf(xf0, xf0, yy), s1 = fmaf(xf1, xf1, yy);
  float s2 = fmaf(xf2, xf2, yy), s3 = fmaf(xf3, xf3, yy);

  float m0 = BIGF, m1 = BIGF, m2 = BIGF, m3 = BIGF;
  #pragma unroll
  for (int m = 0; m < NM; m += 2) {
    float4 c0 = sp[m], c1 = sp[m + 1];
    { float base = fmaf(c0.z, yf, c0.w);
      m0 = fminf(m0, fmaf(c0.x, s0, fmaf(c0.y, xf0, base)));
      m1 = fminf(m1, fmaf(c0.x, s1, fmaf(c0.y, xf1, base)));
      m2 = fminf(m2, fmaf(c0.x, s2, fmaf(c0.y, xf2, base)));
      m3 = fminf(m3, fmaf(c0.x, s3, fmaf(c0.y, xf3, base))); }
    { float base = fmaf(c1.z, yf, c1.w);
      m0 = fminf(m0, fmaf(c1.x, s0, fmaf(c1.y, xf0, base)));
      m1 = fminf(m1, fmaf(c1.x, s1, fmaf(c1.y, xf1, base)));
      m2 = fminf(m2, fmaf(c1.x, s2, fmaf(c1.y, xf2, base)));
      m3 = fminf(m3, fmaf(c1.x, s3, fmaf(c1.y, xf3, base))); }
  }

  float t0 = (m0 <= 8.0f) ? __expf(-m0) : 0.0f;
  float t1 = (m1 <= 8.0f) ? __expf(-m1) : 0.0f;
  float t2 = (m2 <= 8.0f) ? __expf(-m2) : 0.0f;
  float t3 = (m3 <= 8.0f) ? __expf(-m3) : 0.0f;
  float p0 = fminf(fmaxf(pr4.x, EPSF), 1.0f - EPSF);
  float p1 = fminf(fmaxf(pr4.y, EPSF), 1.0f - EPSF);
  float p2 = fminf(fmaxf(pr4.z, EPSF), 1.0f - EPSF);
  float p3 = fminf(fmaxf(pr4.w, EPSF), 1.0f - EPSF);
  float q0 = 1.0f - p0, q1 = 1.0f - p1, q2 = 1.0f - p2, q3 = 1.0f - p3;
  bool o0 = t0 > 0.5f, o1 = t1 > 0.5f, o2 = t2 > 0.5f, o3 = t3 > 0.5f;
  float lg0 = __logf(o0 ? p0 : q0), lg1 = __logf(o1 ? p1 : q1);
  float lg2 = __logf(o2 ? p2 : q2), lg3 = __logf(o3 ? p3 : q3);
  float cf0 = o0 ? (-0.25f * q0 * q0 * t0) : (-0.75f * p0 * p0 * (1.0f - t0));
  float cf1 = o1 ? (-0.25f * q1 * q1 * t1) : (-0.75f * p1 * p1 * (1.0f - t1));
  float cf2 = o2 ? (-0.25f * q2 * q2 * t2) : (-0.75f * p2 * p2 * (1.0f - t2));
  float cf3 = o3 ? (-0.25f * q3 * q3 * t3) : (-0.75f * p3 * p3 * (1.0f - t3));
  float loss = fmaf(cf0, lg0, cf1 * lg1) + fmaf(cf2, lg2, cf3 * lg3);

  int cnt = __popcll(__ballot(o0)) + __popcll(__ballot(o1)) +
            __popcll(__ballot(o2)) + __popcll(__ballot(o3));
  #pragma unroll
  for (int off = 32; off > 0; off >>= 1) loss += __shfl_down(loss, off);
  if (lane == 0) {                         // per-wave partials via coherent atomics
    atomicAdd(&acc[0 * 16 + b], (double)loss);
    atomicAdd(&acc[1 * 16 + b], (double)cnt);
  }

  // ---- cells: blocks bx<16, wave owns box m = bx*4+wave of image b ----
  if (bx < 16) {
    int m = bx * 4 + wave;        // 0..63
    int lbox = b * NM + lane;
    bool valid; int gx, gy; float cx, cy, bw, bh;
    box_geom4(bboxes, labels, lbox, valid, gx, gy, cx, cy, bw, bh);
    int lab = labels[lbox]; lab = lab < 0 ? 0 : (lab > NC - 1 ? NC - 1 : lab);

    int   valid_m = __shfl((int)valid, m);
    int   gx_m = __shfl(gx, m), gy_m = __shfl(gy, m);
    float cx_m = __shfl(cx, m), cy_m = __shfl(cy, m);
    float bw_m = __shfl(bw, m), bh_m = __shfl(bh, m);

    if (valid_m) {
      bool maps = valid && (gx == gx_m) && (gy == gy_m);
      unsigned long long mk = __ballot(maps);         // valid boxes on this cell
      if ((63 - __clzll(mk)) == m) {                  // highest m wins == atomicMax
        unsigned long long cm = maps ? (1ull << lab) : 0ull;
        #pragma unroll
        for (int o = 1; o < 64; o <<= 1) cm |= __shfl_xor(cm, o);
        int celloff = gy_m * WW + gx_m;
        float csum = 0.0f;
        if (lane < NC) {
          float x = pred_classes[(size_t)b * NC * HW + (size_t)lane * HW + celloff];
          float s = 1.0f / (1.0f + __expf(-x));
          float pc = fminf(fmaxf(s, EPSF), 1.0f - EPSF);
          float omc = 1.0f - pc;
          csum = ((cm >> lane) & 1ull) ? (-0.25f * omc * omc * __logf(pc))
                                       : (-0.75f * pc * pc * __logf(omc));
        }
        #pragma unroll
        for (int o = 32; o > 0; o >>= 1) csum += __shfl_down(csum, o);
        if (lane == 0) {
          float dxv = (cx_m - ((float)gx_m + 0.5f) * STRIDE) * 0.25f;
          float dyv = (cy_m - ((float)gy_m + 0.5f) * STRIDE) * 0.25f;
          float dwv = __logf(bw_m * 0.25f + 1e-6f);
          float dhv = __logf(bh_m * 0.25f + 1e-6f);
          const float* pb = pred_boxes + (size_t)b * 4 * HW + celloff;
          float l1 = fabsf(pb[0] - dxv) + fabsf(pb[HW] - dyv) +
                     fabsf(pb[2 * HW] - dwv) + fabsf(pb[3 * HW] - dhv);
          atomicAdd(&acc[2 * 16 + b], (double)l1);
          atomicAdd(&acc[3 * 16 + b], 1.0);
          atomicAdd(&acc[4 * 16 + b], (double)csum);
          atomicAdd(&acc[5 * 16 + b], (double)__popcll(cm));
        }
      }
    }
  }

  // ---- ticket + last-block finalize (atomic-only coherence, no fences) ----
  asm volatile("s_waitcnt vmcnt(0)" ::: "memory");   // this wave's atomics performed
  __syncthreads();                                   // whole block done
  if (tid == 0) {
    unsigned int old = atomicAdd(ticket, 1u);
    islast = (old == NBLK - 1) ? 1 : 0;
  }
  __syncthreads();
  if (!islast) return;

  if (tid < 96) fin[tid] = atomicAdd(&acc[tid], 0.0);  // coherent read of slots
  __syncthreads();
  if (tid == 0) {
    double HS = 0, HC = 0, L1 = 0, MC = 0, CS = 0, CP = 0;
    #pragma unroll
    for (int i = 0; i < 16; ++i) {
      HS += fin[i];      HC += fin[16 + i];
      L1 += fin[32 + i]; MC += fin[48 + i];
      CS += fin[64 + i]; CP += fin[80 + i];
    }
    double nph = HC < 1.0 ? 1.0 : HC;
    float heat = (float)(HS / nph);
    float box = 0.0f, cls = 0.0f;
    if (MC > 1.5) {                         // MC integral: num_pos > 1
      box = (float)(L1 / MC);
      double c = CP < 1.0 ? 1.0 : CP;
      cls = (float)(CS / c);
    }
    out[0] = heat + box + cls;
  }
}

extern "C" void kernel_launch(void* const* d_in, const int* in_sizes, int n_in,
                              void* d_out, int out_size, void* d_ws, size_t ws_size,
                              hipStream_t stream) {
  const float*  pred_heat    = (const float*)d_in[0];   // (16,1,160,160)
  const float*  pred_boxes   = (const float*)d_in[1];   // (16,4,160,160)
  const float*  pred_classes = (const float*)d_in[2];   // (16,43,160,160)
  const float4* bboxes       = (const float4*)d_in[3];  // (16,64,4)
  const int*    labels       = (const int*)d_in[4];     // (16,64)

  char* ws = (char*)d_ws;
  double* acc = (double*)ws;                         // 96 * 8 = 768 B
  unsigned int* ticket = (unsigned int*)(ws + 768);  // 4 B

  hipMemsetAsync(ws, 0, 772, stream);                // zero acc + ticket each call
  dim3 grid(BLKX, NB);
  k_all<<<grid, 256, 0, stream>>>(pred_heat, pred_boxes, pred_classes,
                                  bboxes, labels, acc, ticket, (float*)d_out);
}

// Round 8
// 13.607 us; speedup vs baseline: 2.7766x; 2.7766x over previous
//
#include <hip/hip_runtime.h>

#define HH 160
#define WW 160
#define HW (HH*WW)
#define NB 16
#define NM 64
#define NC 43
#define BLKX 25                  // blocks per image, 1024 px each (256 thr x 4 px)
#define NHEAT (NB*BLKX)          // 400 heat partials (float2)
#define NCELL (NB*16)            // 256 cells partials (float4)

constexpr float STRIDE = 4.0f;   // 640 / 160
constexpr float EPSF = 1e-7f;
constexpr float BIGF = 3.4e38f;

// Shared geometry: must be bit-identical everywhere it is evaluated.
__device__ __forceinline__ void box_geom4(const float4* __restrict__ bb4,
                                          const int* __restrict__ labels, int t,
                                          bool& valid, int& gx, int& gy,
                                          float& cx, float& cy, float& bw, float& bh) {
  float4 v = bb4[t];
  cx = (v.x + v.z) * 0.5f;
  cy = (v.y + v.w) * 0.5f;
  bw = v.z - v.x;
  bh = v.w - v.y;
  int lab = labels[t];
  valid = (lab >= 0) && ((v.x + v.y + v.z + v.w) > 0.0f) && (bw > 0.0f) && (bh > 0.0f);
  int tgx = (int)(cx * 0.25f);            // /4 exact; trunc matches astype(int32)
  int tgy = (int)(cy * 0.25f);
  gx = tgx < 0 ? 0 : (tgx > WW - 1 ? WW - 1 : tgx);
  gy = tgy < 0 ? 0 : (tgy > HH - 1 ? HH - 1 : tgy);
}

// Heat focal (all blocks, 4 px/thread, polynomial distance) + winner-cell losses
// (bx<16, wave owns box m=bx*4+wave). Per-BLOCK partials only. No fences/atomics.
__global__ __launch_bounds__(256) void k_fused(const float* __restrict__ pred_heat,
                                               const float* __restrict__ pred_boxes,
                                               const float* __restrict__ pred_classes,
                                               const float4* __restrict__ bboxes,
                                               const int* __restrict__ labels,
                                               float2* __restrict__ heatp,
                                               float4* __restrict__ cellsp) {
  __shared__ float4 sp[NM];                // (z, -2z*gx, -2z*gy, z*(gx^2+gy^2) | NaN)
  __shared__ float lred[4];
  __shared__ int nred[4];
  __shared__ float4 cred[4];

  int b = blockIdx.y, bx = blockIdx.x;
  int tid = threadIdx.x;
  int wave = tid >> 6, lane = tid & 63;

  if (tid < NM) {
    int t = b * NM + tid;
    bool valid; int gx, gy; float cx, cy, bw, bh;
    box_geom4(bboxes, labels, t, valid, gx, gy, cx, cy, bw, bh);
    float rf = fmaxf(sqrtf(bw * bh) * 0.25f, 2.0f);   // fmax(NaN,2)=2 for junk boxes
    float r = (float)(int)rf;
    float z = 2.0f / (r * r);              // 1/(2*sigma^2); covered iff a <= 8
    float gxf = (float)gx, gyf = (float)gy;
    float4 p;
    p.x = z;
    p.y = -2.0f * z * gxf;
    p.z = -2.0f * z * gyf;
    p.w = valid ? z * fmaf(gxf, gxf, gyf * gyf) : __int_as_float(0x7fc00000);
    sp[tid] = p;                           // NaN K => a=NaN => v_min_f32 skips (IEEE)
  }
  __syncthreads();

  // ---- heat: 4 px/thread (4-aligned chunk never straddles a row; 4|160) ----
  int pixbase = bx * 1024 + tid * 4;       // within image
  int idx = b * HW + pixbase;
  float4 pr4 = *(const float4*)(pred_heat + idx);    // coalesced 16B, issued early
  int row = pixbase / WW;
  float xf0 = (float)(pixbase - row * WW);
  float yf = (float)row;
  float xf1 = xf0 + 1.0f, xf2 = xf0 + 2.0f, xf3 = xf0 + 3.0f;
  float yy = yf * yf;
  float s0 = fmaf(xf0, xf0, yy), s1 = fmaf(xf1, xf1, yy);
  float s2 = fmaf(xf2, xf2, yy), s3 = fmaf(xf3, xf3, yy);

  float m0 = BIGF, m1 = BIGF, m2 = BIGF, m3 = BIGF;
  #pragma unroll
  for (int m = 0; m < NM; m += 2) {
    float4 c0 = sp[m], c1 = sp[m + 1];
    { float base = fmaf(c0.z, yf, c0.w);
      m0 = fminf(m0, fmaf(c0.x, s0, fmaf(c0.y, xf0, base)));
      m1 = fminf(m1, fmaf(c0.x, s1, fmaf(c0.y, xf1, base)));
      m2 = fminf(m2, fmaf(c0.x, s2, fmaf(c0.y, xf2, base)));
      m3 = fminf(m3, fmaf(c0.x, s3, fmaf(c0.y, xf3, base))); }
    { float base = fmaf(c1.z, yf, c1.w);
      m0 = fminf(m0, fmaf(c1.x, s0, fmaf(c1.y, xf0, base)));
      m1 = fminf(m1, fmaf(c1.x, s1, fmaf(c1.y, xf1, base)));
      m2 = fminf(m2, fmaf(c1.x, s2, fmaf(c1.y, xf2, base)));
      m3 = fminf(m3, fmaf(c1.x, s3, fmaf(c1.y, xf3, base))); }
  }

  float t0 = (m0 <= 8.0f) ? __expf(-m0) : 0.0f;
  float t1 = (m1 <= 8.0f) ? __expf(-m1) : 0.0f;
  float t2 = (m2 <= 8.0f) ? __expf(-m2) : 0.0f;
  float t3 = (m3 <= 8.0f) ? __expf(-m3) : 0.0f;
  float p0 = fminf(fmaxf(pr4.x, EPSF), 1.0f - EPSF);
  float p1 = fminf(fmaxf(pr4.y, EPSF), 1.0f - EPSF);
  float p2 = fminf(fmaxf(pr4.z, EPSF), 1.0f - EPSF);
  float p3 = fminf(fmaxf(pr4.w, EPSF), 1.0f - EPSF);
  float q0 = 1.0f - p0, q1 = 1.0f - p1, q2 = 1.0f - p2, q3 = 1.0f - p3;
  bool o0 = t0 > 0.5f, o1 = t1 > 0.5f, o2 = t2 > 0.5f, o3 = t3 > 0.5f;
  float lg0 = __logf(o0 ? p0 : q0), lg1 = __logf(o1 ? p1 : q1);
  float lg2 = __logf(o2 ? p2 : q2), lg3 = __logf(o3 ? p3 : q3);
  float cf0 = o0 ? (-0.25f * q0 * q0 * t0) : (-0.75f * p0 * p0 * (1.0f - t0));
  float cf1 = o1 ? (-0.25f * q1 * q1 * t1) : (-0.75f * p1 * p1 * (1.0f - t1));
  float cf2 = o2 ? (-0.25f * q2 * q2 * t2) : (-0.75f * p2 * p2 * (1.0f - t2));
  float cf3 = o3 ? (-0.25f * q3 * q3 * t3) : (-0.75f * p3 * p3 * (1.0f - t3));
  float loss = fmaf(cf0, lg0, cf1 * lg1) + fmaf(cf2, lg2, cf3 * lg3);

  int cnt = __popcll(__ballot(o0)) + __popcll(__ballot(o1)) +
            __popcll(__ballot(o2)) + __popcll(__ballot(o3));
  #pragma unroll
  for (int off = 32; off > 0; off >>= 1) loss += __shfl_down(loss, off);
  if (lane == 0) { lred[wave] = loss; nred[wave] = cnt; }
  __syncthreads();
  if (tid == 0)
    heatp[b * BLKX + bx] = make_float2(lred[0] + lred[1] + lred[2] + lred[3],
                                       (float)(nred[0] + nred[1] + nred[2] + nred[3]));

  // ---- cells: blocks bx<16, wave owns box m = bx*4+wave of image b ----
  if (bx < 16) {
    int m = bx * 4 + wave;        // 0..63
    int lbox = b * NM + lane;
    bool valid; int gx, gy; float cx, cy, bw, bh;
    box_geom4(bboxes, labels, lbox, valid, gx, gy, cx, cy, bw, bh);
    int lab = labels[lbox]; lab = lab < 0 ? 0 : (lab > NC - 1 ? NC - 1 : lab);

    int   valid_m = __shfl((int)valid, m);
    int   gx_m = __shfl(gx, m), gy_m = __shfl(gy, m);
    float cx_m = __shfl(cx, m), cy_m = __shfl(cy, m);
    float bw_m = __shfl(bw, m), bh_m = __shfl(bh, m);

    float l1 = 0.0f, csum = 0.0f;
    float cnt1 = 0.0f, npos = 0.0f;
    if (valid_m) {
      bool maps = valid && (gx == gx_m) && (gy == gy_m);
      unsigned long long mk = __ballot(maps);         // valid boxes on this cell
      if ((63 - __clzll(mk)) == m) {                  // highest m wins == atomicMax
        unsigned long long cm = maps ? (1ull << lab) : 0ull;
        #pragma unroll
        for (int o = 1; o < 64; o <<= 1) cm |= __shfl_xor(cm, o);
        int celloff = gy_m * WW + gx_m;
        if (lane < NC) {
          float x = pred_classes[(size_t)b * NC * HW + (size_t)lane * HW + celloff];
          float s = 1.0f / (1.0f + __expf(-x));
          float pc = fminf(fmaxf(s, EPSF), 1.0f - EPSF);
          float omc = 1.0f - pc;
          csum = ((cm >> lane) & 1ull) ? (-0.25f * omc * omc * __logf(pc))
                                       : (-0.75f * pc * pc * __logf(omc));
        }
        #pragma unroll
        for (int o = 32; o > 0; o >>= 1) csum += __shfl_down(csum, o);
        if (lane == 0) {
          float dxv = (cx_m - ((float)gx_m + 0.5f) * STRIDE) * 0.25f;
          float dyv = (cy_m - ((float)gy_m + 0.5f) * STRIDE) * 0.25f;
          float dwv = __logf(bw_m * 0.25f + 1e-6f);
          float dhv = __logf(bh_m * 0.25f + 1e-6f);
          const float* pb = pred_boxes + (size_t)b * 4 * HW + celloff;
          l1 = fabsf(pb[0] - dxv) + fabsf(pb[HW] - dyv) +
               fabsf(pb[2 * HW] - dwv) + fabsf(pb[3 * HW] - dhv);
          cnt1 = 1.0f;
          npos = (float)__popcll(cm);
        }
      }
    }
    if (lane == 0) cred[wave] = make_float4(l1, cnt1, csum, npos);
    __syncthreads();
    if (tid == 0) {
      float4 a = cred[0], c1 = cred[1], c2 = cred[2], c3 = cred[3];
      cellsp[b * 16 + bx] = make_float4(a.x + c1.x + c2.x + c3.x,
                                        a.y + c1.y + c2.y + c3.y,
                                        a.z + c1.z + c2.z + c3.z,
                                        a.w + c1.w + c2.w + c3.w);
    }
  }
}

// Single-block tree reduce of 400 f2 + 256 f4 partials + finalize.
__global__ __launch_bounds__(256) void k_final(const float2* __restrict__ heatp,
                                               const float4* __restrict__ cellsp,
                                               float* __restrict__ out) {
  int t = threadIdx.x;
  double hs = 0.0, hc = 0.0, l1 = 0.0, mc = 0.0, cs = 0.0, cp = 0.0;
  for (int i = t; i < NHEAT; i += 256) {
    float2 v = heatp[i];
    hs += (double)v.x; hc += (double)v.y;
  }
  if (t < NCELL) {
    float4 e = cellsp[t];
    l1 = (double)e.x; mc = (double)e.y; cs = (double)e.z; cp = (double)e.w;
  }
  #pragma unroll
  for (int off = 32; off > 0; off >>= 1) {
    hs += __shfl_down(hs, off); hc += __shfl_down(hc, off);
    l1 += __shfl_down(l1, off); mc += __shfl_down(mc, off);
    cs += __shfl_down(cs, off); cp += __shfl_down(cp, off);
  }
  __shared__ double fin[4][6];
  int wave = t >> 6;
  if ((t & 63) == 0) {
    fin[wave][0] = hs; fin[wave][1] = hc; fin[wave][2] = l1;
    fin[wave][3] = mc; fin[wave][4] = cs; fin[wave][5] = cp;
  }
  __syncthreads();
  if (t == 0) {
    double HS = 0, HC = 0, L1 = 0, MC = 0, CS = 0, CP = 0;
    #pragma unroll
    for (int i = 0; i < 4; ++i) {
      HS += fin[i][0]; HC += fin[i][1]; L1 += fin[i][2];
      MC += fin[i][3]; CS += fin[i][4]; CP += fin[i][5];
    }
    double nph = HC < 1.0 ? 1.0 : HC;
    float heat = (float)(HS / nph);
    float box = 0.0f, cls = 0.0f;
    if (MC > 1.5) {                         // MC integral: num_pos > 1
      box = (float)(L1 / MC);
      double c = CP < 1.0 ? 1.0 : CP;
      cls = (float)(CS / c);
    }
    out[0] = heat + box + cls;
  }
}

extern "C" void kernel_launch(void* const* d_in, const int* in_sizes, int n_in,
                              void* d_out, int out_size, void* d_ws, size_t ws_size,
                              hipStream_t stream) {
  const float*  pred_heat    = (const float*)d_in[0];   // (16,1,160,160)
  const float*  pred_boxes   = (const float*)d_in[1];   // (16,4,160,160)
  const float*  pred_classes = (const float*)d_in[2];   // (16,43,160,160)
  const float4* bboxes       = (const float4*)d_in[3];  // (16,64,4)
  const int*    labels       = (const int*)d_in[4];     // (16,64)

  char* ws = (char*)d_ws;
  float2* heatp  = (float2*)ws;                // 400 * 8  = 3200 B
  float4* cellsp = (float4*)(ws + 3200);       // 256 * 16 = 4096 B (16B aligned)

  dim3 grid(BLKX, NB);
  k_fused<<<grid, 256, 0, stream>>>(pred_heat, pred_boxes, pred_classes,
                                    bboxes, labels, heatp, cellsp);
  k_final<<<1, 256, 0, stream>>>(heatp, cellsp, (float*)d_out);
}